// Round 1
// baseline (2983.694 us; speedup 1.0000x reference)
//
#include <hip/hip_runtime.h>

// Neural-ODE (dopri5 reference) solved with fixed-step RK4, h <= 0.04.
// Each of B*P = 20800 points is an independent 64-dim autonomous ODE:
//   f(y) = tanh(y @ W1 + b1) @ W2 + b2
// Block = 256 threads (4 waves), each wave integrates 4 points; lane d owns
// dim d of its wave's 4 points. W1/W2 staged in LDS; y/h exchanged via
// per-wave float4 LDS buffers (broadcast reads, conflict-free weight reads).

#define NB 64       // batches
#define NPT 325     // points per batch
#define ND 64       // latent dim
#define NH 128      // hidden dim
#define NT 24       // output times
#define WPTS 4      // points per wave
#define NWAVE 4     // waves per block
#define BPTS (WPTS * NWAVE)                 // 16 points per block
#define NCHUNK ((NPT + BPTS - 1) / BPTS)    // 21 chunks per batch

struct Smem {
  float w1[ND * NH];         // [i][j] row-major (32 KB)
  float w2[NH * ND];         // [j][d] row-major (32 KB)
  float b1[NH];
  float b2[ND];
  float4 ybuf[NWAVE * ND];   // [wave][dim]  -> 4 points (4 KB)
  float4 hbuf[NWAVE * NH];   // [wave][hid]  -> 4 points (8 KB)
};

__device__ __forceinline__ float fast_tanh(float x) {
  x = fminf(fmaxf(x, -12.0f), 12.0f);          // avoid exp overflow; tanh saturated anyway
  float e = __expf(2.0f * x);
  return (e - 1.0f) * __builtin_amdgcn_rcpf(e + 1.0f);
}

// One evaluation of f for this wave's 4 points; yin.{x,y,z,w} = dim `lane`
// of points 0..3. Two __syncthreads per call (all waves run identical counts).
__device__ __forceinline__ float4 feval(Smem& sm, int wave, int lane, float4 yin) {
  sm.ybuf[wave * ND + lane] = yin;
  __syncthreads();

  const float ba = sm.b1[lane];
  const float bb = sm.b1[lane + 64];
  float a0 = ba, a1 = ba, a2 = ba, a3 = ba;
  float c0 = bb, c1 = bb, c2 = bb, c3 = bb;
  const float4* yb = &sm.ybuf[wave * ND];
#pragma unroll 8
  for (int i = 0; i < ND; ++i) {
    float4 yv = yb[i];                       // broadcast ds_read_b128
    float wa = sm.w1[i * NH + lane];         // lanes consecutive: conflict-free
    float wb = sm.w1[i * NH + lane + 64];
    a0 = fmaf(yv.x, wa, a0);
    a1 = fmaf(yv.y, wa, a1);
    a2 = fmaf(yv.z, wa, a2);
    a3 = fmaf(yv.w, wa, a3);
    c0 = fmaf(yv.x, wb, c0);
    c1 = fmaf(yv.y, wb, c1);
    c2 = fmaf(yv.z, wb, c2);
    c3 = fmaf(yv.w, wb, c3);
  }
  sm.hbuf[wave * NH + lane] =
      make_float4(fast_tanh(a0), fast_tanh(a1), fast_tanh(a2), fast_tanh(a3));
  sm.hbuf[wave * NH + lane + 64] =
      make_float4(fast_tanh(c0), fast_tanh(c1), fast_tanh(c2), fast_tanh(c3));
  __syncthreads();

  const float bo = sm.b2[lane];
  float f0 = bo, f1 = bo, f2 = bo, f3 = bo;
  const float4* hb = &sm.hbuf[wave * NH];
#pragma unroll 8
  for (int j = 0; j < NH; ++j) {
    float4 hv = hb[j];                       // broadcast
    float w = sm.w2[j * ND + lane];          // conflict-free
    f0 = fmaf(hv.x, w, f0);
    f1 = fmaf(hv.y, w, f1);
    f2 = fmaf(hv.z, w, f2);
    f3 = fmaf(hv.w, w, f3);
  }
  return make_float4(f0, f1, f2, f3);
}

__global__ __launch_bounds__(256, 2) void node_rk4_kernel(
    const float* __restrict__ y0g, const float* __restrict__ tsg,
    const float* __restrict__ W1g, const float* __restrict__ b1g,
    const float* __restrict__ W2g, const float* __restrict__ b2g,
    float* __restrict__ outg) {
  __shared__ Smem sm;
  const int tid = threadIdx.x;
  const int wave = tid >> 6;
  const int lane = tid & 63;

#pragma unroll 4
  for (int i = tid; i < ND * NH; i += 256) sm.w1[i] = W1g[i];
#pragma unroll 4
  for (int i = tid; i < NH * ND; i += 256) sm.w2[i] = W2g[i];
  if (tid < NH) sm.b1[tid] = b1g[tid];
  if (tid < ND) sm.b2[tid] = b2g[tid];
  // first feval's internal barrier orders these LDS writes before any read

  const int b = blockIdx.x / NCHUNK;
  const int chunk = blockIdx.x - b * NCHUNK;
  const int pb = chunk * BPTS + wave * WPTS;

  const bool v0 = (pb + 0) < NPT;
  const bool v1 = (pb + 1) < NPT;
  const bool v2 = (pb + 2) < NPT;
  const bool v3 = (pb + 3) < NPT;
  const int q0 = b * NPT + min(pb + 0, NPT - 1);
  const int q1 = b * NPT + min(pb + 1, NPT - 1);
  const int q2 = b * NPT + min(pb + 2, NPT - 1);
  const int q3 = b * NPT + min(pb + 3, NPT - 1);

  float4 y;
  y.x = y0g[q0 * ND + lane];
  y.y = y0g[q1 * ND + lane];
  y.z = y0g[q2 * ND + lane];
  y.w = y0g[q3 * ND + lane];

  float tprev = tsg[b];  // ts[0][b]; y0 is the state AT ts[0]

  // k = 0 output is y0 itself
  if (v0) outg[(size_t)q0 * (ND * NT) + lane * NT + 0] = y.x;
  if (v1) outg[(size_t)q1 * (ND * NT) + lane * NT + 0] = y.y;
  if (v2) outg[(size_t)q2 * (ND * NT) + lane * NT + 0] = y.z;
  if (v3) outg[(size_t)q3 * (ND * NT) + lane * NT + 0] = y.w;

  for (int k = 1; k < NT; ++k) {
    float tnext = tsg[k * NB + b];
    float dt = tnext - tprev;
    int n = (int)ceilf(dt * 25.0f);  // substeps so h <= 0.04
    n = n < 1 ? 1 : n;
    float h = dt / (float)n;
    float h2 = 0.5f * h;
    float h6 = h * (1.0f / 6.0f);

    for (int s = 0; s < n; ++s) {
      float4 f1 = feval(sm, wave, lane, y);
      float4 yt = make_float4(fmaf(h2, f1.x, y.x), fmaf(h2, f1.y, y.y),
                              fmaf(h2, f1.z, y.z), fmaf(h2, f1.w, y.w));
      float4 f2 = feval(sm, wave, lane, yt);
      yt = make_float4(fmaf(h2, f2.x, y.x), fmaf(h2, f2.y, y.y),
                       fmaf(h2, f2.z, y.z), fmaf(h2, f2.w, y.w));
      float4 f3 = feval(sm, wave, lane, yt);
      yt = make_float4(fmaf(h, f3.x, y.x), fmaf(h, f3.y, y.y),
                       fmaf(h, f3.z, y.z), fmaf(h, f3.w, y.w));
      float4 f4 = feval(sm, wave, lane, yt);
      y.x = fmaf(h6, f1.x + 2.0f * f2.x + 2.0f * f3.x + f4.x, y.x);
      y.y = fmaf(h6, f1.y + 2.0f * f2.y + 2.0f * f3.y + f4.y, y.y);
      y.z = fmaf(h6, f1.z + 2.0f * f2.z + 2.0f * f3.z + f4.z, y.z);
      y.w = fmaf(h6, f1.w + 2.0f * f2.w + 2.0f * f3.w + f4.w, y.w);
    }

    if (v0) outg[(size_t)q0 * (ND * NT) + lane * NT + k] = y.x;
    if (v1) outg[(size_t)q1 * (ND * NT) + lane * NT + k] = y.y;
    if (v2) outg[(size_t)q2 * (ND * NT) + lane * NT + k] = y.z;
    if (v3) outg[(size_t)q3 * (ND * NT) + lane * NT + k] = y.w;
    tprev = tnext;
  }
}

extern "C" void kernel_launch(void* const* d_in, const int* in_sizes, int n_in,
                              void* d_out, int out_size, void* d_ws, size_t ws_size,
                              hipStream_t stream) {
  const float* y0 = (const float*)d_in[0];
  const float* ts = (const float*)d_in[1];
  const float* W1 = (const float*)d_in[2];
  const float* b1 = (const float*)d_in[3];
  const float* W2 = (const float*)d_in[4];
  const float* b2 = (const float*)d_in[5];
  float* out = (float*)d_out;

  dim3 grid(NB * NCHUNK);   // 64 batches x 21 point-chunks = 1344 blocks
  dim3 block(256);
  hipLaunchKernelGGL(node_rk4_kernel, grid, block, 0, stream,
                     y0, ts, W1, b1, W2, b2, out);
}

// Round 2
// 2703.765 us; speedup vs baseline: 1.1035x; 1.1035x over previous
//
#include <hip/hip_runtime.h>

// Neural-ODE (dopri5 reference) via fixed-step RK4, h <= 0.04.
// f(y) = tanh(y @ W1 + b1) @ W2 + b2, 20800 independent 64-dim points.
// Wave-autonomous: each wave integrates 8 points of one batch; NO per-feval
// __syncthreads (y/h scratch is per-wave; LDS ops in-order within a wave).
// Weights pair-interleaved in LDS so weight reads are conflict-free b64.
// LDS: w1i 32KB + w2i 32KB + 4KB scratch x 4 waves = 80KB -> 2 blocks/CU.

#define NB 64
#define NPT 325
#define ND 64
#define NH 128
#define NT 24
#define WPTS 8
#define NWAVE 4
#define WAVES_PER_BATCH 41                    // ceil(325/8)
#define TOTAL_WAVES (NB * WAVES_PER_BATCH)    // 2624
#define NBLOCKS ((TOTAL_WAVES + NWAVE - 1) / NWAVE)  // 656

struct Smem {
  float w1i[ND * NH];      // w1i[i*128 + 2*j + h] = W1[i][j + 64*h]
  float w2i[NH * ND];      // w2i[jp*128 + 2*d + r] = W2[2*jp + r][d]
  float4 scr[NWAVE][256];  // per-wave: y at slots [2i..2i+1] (i<64); h overlays [2j..2j+1] (j<128)
};

__device__ __forceinline__ float fast_tanh(float x) {
  x = fminf(fmaxf(x, -12.0f), 12.0f);
  float e = __expf(2.0f * x);
  return (e - 1.0f) * __builtin_amdgcn_rcpf(e + 1.0f);
}

// yin[8] -> fout[8]: dim `lane` of this wave's 8 points. No block barriers.
__device__ __forceinline__ void feval(const Smem& sm, float4* scr, int lane,
                                      float b1a, float b1b, float b2v,
                                      const float* yin, float* fout) {
  scr[2 * lane]     = make_float4(yin[0], yin[1], yin[2], yin[3]);
  scr[2 * lane + 1] = make_float4(yin[4], yin[5], yin[6], yin[7]);

  float aA[8], aB[8];
#pragma unroll
  for (int p = 0; p < 8; ++p) { aA[p] = b1a; aB[p] = b1b; }

  const float2* w1row = (const float2*)&sm.w1i[2 * lane];
#pragma unroll 8
  for (int i = 0; i < ND; ++i) {
    float4 v0 = scr[2 * i];        // broadcast
    float4 v1 = scr[2 * i + 1];    // broadcast
    float2 w = w1row[i * 64];      // ds_read_b64, conflict-free
    aA[0] = fmaf(v0.x, w.x, aA[0]); aA[1] = fmaf(v0.y, w.x, aA[1]);
    aA[2] = fmaf(v0.z, w.x, aA[2]); aA[3] = fmaf(v0.w, w.x, aA[3]);
    aA[4] = fmaf(v1.x, w.x, aA[4]); aA[5] = fmaf(v1.y, w.x, aA[5]);
    aA[6] = fmaf(v1.z, w.x, aA[6]); aA[7] = fmaf(v1.w, w.x, aA[7]);
    aB[0] = fmaf(v0.x, w.y, aB[0]); aB[1] = fmaf(v0.y, w.y, aB[1]);
    aB[2] = fmaf(v0.z, w.y, aB[2]); aB[3] = fmaf(v0.w, w.y, aB[3]);
    aB[4] = fmaf(v1.x, w.y, aB[4]); aB[5] = fmaf(v1.y, w.y, aB[5]);
    aB[6] = fmaf(v1.z, w.y, aB[6]); aB[7] = fmaf(v1.w, w.y, aB[7]);
  }

  // tanh -> h; overlay onto scr (y is dead; same-wave in-order LDS)
  float4 hA0 = make_float4(fast_tanh(aA[0]), fast_tanh(aA[1]), fast_tanh(aA[2]), fast_tanh(aA[3]));
  float4 hA1 = make_float4(fast_tanh(aA[4]), fast_tanh(aA[5]), fast_tanh(aA[6]), fast_tanh(aA[7]));
  float4 hB0 = make_float4(fast_tanh(aB[0]), fast_tanh(aB[1]), fast_tanh(aB[2]), fast_tanh(aB[3]));
  float4 hB1 = make_float4(fast_tanh(aB[4]), fast_tanh(aB[5]), fast_tanh(aB[6]), fast_tanh(aB[7]));
  scr[2 * lane]            = hA0;  // j = lane
  scr[2 * lane + 1]        = hA1;
  scr[2 * (lane + 64)]     = hB0;  // j = lane + 64
  scr[2 * (lane + 64) + 1] = hB1;

  float f[8];
#pragma unroll
  for (int p = 0; p < 8; ++p) f[p] = b2v;

  const float2* w2row = (const float2*)&sm.w2i[2 * lane];
#pragma unroll 8
  for (int jp = 0; jp < 64; ++jp) {
    float4 g0 = scr[4 * jp];       // j = 2jp, pts 0-3 (broadcast)
    float4 g1 = scr[4 * jp + 1];   // j = 2jp, pts 4-7
    float4 g2 = scr[4 * jp + 2];   // j = 2jp+1, pts 0-3
    float4 g3 = scr[4 * jp + 3];   // j = 2jp+1, pts 4-7
    float2 w = w2row[jp * 64];     // (W2[2jp][lane], W2[2jp+1][lane])
    f[0] = fmaf(g0.x, w.x, f[0]); f[1] = fmaf(g0.y, w.x, f[1]);
    f[2] = fmaf(g0.z, w.x, f[2]); f[3] = fmaf(g0.w, w.x, f[3]);
    f[4] = fmaf(g1.x, w.x, f[4]); f[5] = fmaf(g1.y, w.x, f[5]);
    f[6] = fmaf(g1.z, w.x, f[6]); f[7] = fmaf(g1.w, w.x, f[7]);
    f[0] = fmaf(g2.x, w.y, f[0]); f[1] = fmaf(g2.y, w.y, f[1]);
    f[2] = fmaf(g2.z, w.y, f[2]); f[3] = fmaf(g2.w, w.y, f[3]);
    f[4] = fmaf(g3.x, w.y, f[4]); f[5] = fmaf(g3.y, w.y, f[5]);
    f[6] = fmaf(g3.z, w.y, f[6]); f[7] = fmaf(g3.w, w.y, f[7]);
  }
#pragma unroll
  for (int p = 0; p < 8; ++p) fout[p] = f[p];
}

__global__ __launch_bounds__(256, 2) void node_rk4_kernel(
    const float* __restrict__ y0g, const float* __restrict__ tsg,
    const float* __restrict__ W1g, const float* __restrict__ b1g,
    const float* __restrict__ W2g, const float* __restrict__ b2g,
    float* __restrict__ outg) {
  __shared__ Smem sm;
  const int tid = threadIdx.x;
  const int wave = tid >> 6;
  const int lane = tid & 63;

  // stage weights, pair-interleaved
  for (int idx = tid; idx < ND * NH; idx += 256) {
    int i = idx >> 7, j = idx & 127;
    float v = W1g[idx];
    sm.w1i[(j < 64) ? (i * 128 + 2 * j) : (i * 128 + 2 * (j - 64) + 1)] = v;
  }
  for (int idx = tid; idx < NH * ND; idx += 256) {
    int j = idx >> 6, d = idx & 63;
    sm.w2i[(j >> 1) * 128 + 2 * d + (j & 1)] = W2g[idx];
  }
  __syncthreads();  // the ONLY block barrier

  const float b1a = b1g[lane];
  const float b1b = b1g[lane + 64];
  const float b2v = b2g[lane];

  const int gw = blockIdx.x * NWAVE + wave;  // global wave id
  if (gw >= TOTAL_WAVES) return;
  const int b = gw / WAVES_PER_BATCH;
  const int pb = (gw - b * WAVES_PER_BATCH) * WPTS;

  float4* scr = sm.scr[wave];

  bool v[8];
  int q[8];
#pragma unroll
  for (int p = 0; p < 8; ++p) {
    v[p] = (pb + p) < NPT;
    q[p] = b * NPT + min(pb + p, NPT - 1);
  }

  float y[8];
#pragma unroll
  for (int p = 0; p < 8; ++p) y[p] = y0g[q[p] * ND + lane];

  float tprev = tsg[b];

#pragma unroll
  for (int p = 0; p < 8; ++p)
    if (v[p]) outg[(size_t)q[p] * (ND * NT) + lane * NT + 0] = y[p];

  float ksum[8], yt[8], f[8];

  for (int k = 1; k < NT; ++k) {
    float tnext = tsg[k * NB + b];
    float dt = tnext - tprev;
    int n = (int)ceilf(dt * 25.0f);  // h <= 0.04
    n = n < 1 ? 1 : n;
    float h = dt / (float)n;
    float h2 = 0.5f * h;
    float h6 = h * (1.0f / 6.0f);

    for (int s = 0; s < n; ++s) {
      feval(sm, scr, lane, b1a, b1b, b2v, y, f);   // k1
#pragma unroll
      for (int p = 0; p < 8; ++p) { ksum[p] = f[p]; yt[p] = fmaf(h2, f[p], y[p]); }
      feval(sm, scr, lane, b1a, b1b, b2v, yt, f);  // k2
#pragma unroll
      for (int p = 0; p < 8; ++p) { ksum[p] = fmaf(2.0f, f[p], ksum[p]); yt[p] = fmaf(h2, f[p], y[p]); }
      feval(sm, scr, lane, b1a, b1b, b2v, yt, f);  // k3
#pragma unroll
      for (int p = 0; p < 8; ++p) { ksum[p] = fmaf(2.0f, f[p], ksum[p]); yt[p] = fmaf(h, f[p], y[p]); }
      feval(sm, scr, lane, b1a, b1b, b2v, yt, f);  // k4
#pragma unroll
      for (int p = 0; p < 8; ++p) y[p] = fmaf(h6, ksum[p] + f[p], y[p]);
    }

#pragma unroll
    for (int p = 0; p < 8; ++p)
      if (v[p]) outg[(size_t)q[p] * (ND * NT) + lane * NT + k] = y[p];
    tprev = tnext;
  }
}

extern "C" void kernel_launch(void* const* d_in, const int* in_sizes, int n_in,
                              void* d_out, int out_size, void* d_ws, size_t ws_size,
                              hipStream_t stream) {
  const float* y0 = (const float*)d_in[0];
  const float* ts = (const float*)d_in[1];
  const float* W1 = (const float*)d_in[2];
  const float* b1 = (const float*)d_in[3];
  const float* W2 = (const float*)d_in[4];
  const float* b2 = (const float*)d_in[5];
  float* out = (float*)d_out;

  hipLaunchKernelGGL(node_rk4_kernel, dim3(NBLOCKS), dim3(256), 0, stream,
                     y0, ts, W1, b1, W2, b2, out);
}

// Round 3
// 864.855 us; speedup vs baseline: 3.4499x; 3.1263x over previous
//
#include <hip/hip_runtime.h>

// Neural-ODE via fixed-step RK4 (h <= 0.04), f(y) = tanh(y@W1+b1)@W2 + b2.
// MFMA rewrite: one wave integrates 16 points with mfma_f32_16x16x32_f16.
//   A-frag (16x32): lane l holds A[row = l&15][k = (l>>4)*8 + j], j=0..7
//   B-frag (32x16): lane l holds B[k = (l>>4)*8 + j][col = l&15]
//   C/D:            lane l holds D[row = (l>>4)*4 + r][col = l&15]   (m89-verified)
// Weights = fp16 B-frags held in VGPRs (no per-feval weight traffic).
// y/h transposes via per-wave LDS scratch (bank-conflict-free patterns).
// Output staged coalesced [q][k][d] in d_ws, then transposed to [q][d][k].

#define NB 64
#define NPT 325
#define ND 64
#define NH 128
#define NTOUT 24
#define GROUPS_PER_B 21                  // ceil(325/16)
#define NTASK (NB * GROUPS_PER_B)        // 1344 wave-tasks
#define K1_BLOCKS 512
#define YSTRIDE 68                       // 64 + 4 pad (fp32)
#define HSTRIDE 132                      // 128 + 4 pad
#define SCRF (16 * HSTRIDE)              // per-wave scratch floats (2112)

using f16x8 = __attribute__((ext_vector_type(8))) _Float16;
using f32x4 = __attribute__((ext_vector_type(4))) float;

__device__ __forceinline__ float fast_tanh(float x) {
  x = fminf(fmaxf(x, -12.0f), 12.0f);
  float e = __expf(2.0f * x);
  return (e - 1.0f) * __builtin_amdgcn_rcpf(e + 1.0f);
}

template <bool USE_WS>
__global__ __launch_bounds__(256, 2) void node_mfma_kernel(
    const float* __restrict__ y0g, const float* __restrict__ tsg,
    const float* __restrict__ W1g, const float* __restrict__ b1g,
    const float* __restrict__ W2g, const float* __restrict__ b2g,
    float* __restrict__ outg, float* __restrict__ wsg) {
  __shared__ __align__(16) float scrAll[4][SCRF];
  const int tid = threadIdx.x;
  const int wave = tid >> 6;
  const int lane = tid & 63;
  const int c = lane & 15;   // col / point-row selector
  const int g = lane >> 4;   // k-chunk / point-group selector

  const int task = wave * K1_BLOCKS + (int)blockIdx.x;
  if (task >= NTASK) return;
  const int b = task / GROUPS_PER_B;
  const int grp = task - b * GROUPS_PER_B;
  const int p0 = grp * 16;

  // ---- weight fragments (fp16, VGPR-resident) ----
  f16x8 wf1[2][8];  // W1[64x128]: kt in {0,1}, nt in {0..7}
#pragma unroll
  for (int kt = 0; kt < 2; ++kt)
#pragma unroll
    for (int nt = 0; nt < 8; ++nt) {
      const float* src = &W1g[(kt * 32 + g * 8) * NH + nt * 16 + c];
      f16x8 a;
#pragma unroll
      for (int j = 0; j < 8; ++j) a[j] = (_Float16)src[j * NH];
      wf1[kt][nt] = a;
    }
  f16x8 wf2[4][4];  // W2[128x64]: kt in {0..3}, nt in {0..3}
#pragma unroll
  for (int kt = 0; kt < 4; ++kt)
#pragma unroll
    for (int nt = 0; nt < 4; ++nt) {
      const float* src = &W2g[(kt * 32 + g * 8) * ND + nt * 16 + c];
      f16x8 a;
#pragma unroll
      for (int j = 0; j < 8; ++j) a[j] = (_Float16)src[j * ND];
      wf2[kt][nt] = a;
    }

  float b1v[8], b2v[4];
#pragma unroll
  for (int nt = 0; nt < 8; ++nt) b1v[nt] = b1g[nt * 16 + c];
#pragma unroll
  for (int nt = 0; nt < 4; ++nt) b2v[nt] = b2g[nt * 16 + c];

  // ---- state: y[r*4+t] = Y[pt = 4g+r][dim = 16t+c] (D-layout) ----
  bool vr[4];
  int qr[4];
#pragma unroll
  for (int r = 0; r < 4; ++r) {
    int pt = p0 + 4 * g + r;
    vr[r] = pt < NPT;
    qr[r] = b * NPT + min(pt, NPT - 1);
  }
  float y[16];
#pragma unroll
  for (int r = 0; r < 4; ++r)
#pragma unroll
    for (int t = 0; t < 4; ++t) y[r * 4 + t] = y0g[qr[r] * ND + 16 * t + c];

  float* scr = scrAll[wave];

  // f(v) in place: v is D-layout [r*4+t]; wave-local LDS, no barriers.
  auto feval = [&](float* v) {
    // y -> LDS [pt][dim] (2-way bank pattern = free)
#pragma unroll
    for (int r = 0; r < 4; ++r)
#pragma unroll
      for (int t = 0; t < 4; ++t)
        scr[(4 * g + r) * YSTRIDE + 16 * t + c] = v[r * 4 + t];
    // A1 frags: row = pt = c, k = dim = kt*32 + 8g + j
    f16x8 a1[2];
#pragma unroll
    for (int kt = 0; kt < 2; ++kt) {
      const float4* p = (const float4*)&scr[c * YSTRIDE + kt * 32 + 8 * g];
      float4 lo = p[0], hi = p[1];
      f16x8 a;
      a[0] = (_Float16)lo.x; a[1] = (_Float16)lo.y;
      a[2] = (_Float16)lo.z; a[3] = (_Float16)lo.w;
      a[4] = (_Float16)hi.x; a[5] = (_Float16)hi.y;
      a[6] = (_Float16)hi.z; a[7] = (_Float16)hi.w;
      a1[kt] = a;
    }
    // layer 1: D1[pt][hid], acc init = b1
    f32x4 acc1[8];
#pragma unroll
    for (int nt = 0; nt < 8; ++nt) {
      f32x4 acc = {b1v[nt], b1v[nt], b1v[nt], b1v[nt]};
      acc = __builtin_amdgcn_mfma_f32_16x16x32_f16(a1[0], wf1[0][nt], acc, 0, 0, 0);
      acc = __builtin_amdgcn_mfma_f32_16x16x32_f16(a1[1], wf1[1][nt], acc, 0, 0, 0);
      acc1[nt] = acc;
    }
    // tanh -> h scatter to LDS [pt][hid] (overlays y region; in-wave in-order)
#pragma unroll
    for (int nt = 0; nt < 8; ++nt)
#pragma unroll
      for (int r = 0; r < 4; ++r)
        scr[(4 * g + r) * HSTRIDE + 16 * nt + c] = fast_tanh(acc1[nt][r]);
    // A2 frags: row = pt = c, k = hid = kt*32 + 8g + j
    f16x8 a2[4];
#pragma unroll
    for (int kt = 0; kt < 4; ++kt) {
      const float4* p = (const float4*)&scr[c * HSTRIDE + kt * 32 + 8 * g];
      float4 lo = p[0], hi = p[1];
      f16x8 a;
      a[0] = (_Float16)lo.x; a[1] = (_Float16)lo.y;
      a[2] = (_Float16)lo.z; a[3] = (_Float16)lo.w;
      a[4] = (_Float16)hi.x; a[5] = (_Float16)hi.y;
      a[6] = (_Float16)hi.z; a[7] = (_Float16)hi.w;
      a2[kt] = a;
    }
    // layer 2: f[pt][dim], acc init = b2; result back into v (D-layout)
#pragma unroll
    for (int nt = 0; nt < 4; ++nt) {
      f32x4 acc = {b2v[nt], b2v[nt], b2v[nt], b2v[nt]};
#pragma unroll
      for (int kt = 0; kt < 4; ++kt)
        acc = __builtin_amdgcn_mfma_f32_16x16x32_f16(a2[kt], wf2[kt][nt], acc, 0, 0, 0);
#pragma unroll
      for (int r = 0; r < 4; ++r) v[r * 4 + nt] = acc[r];
    }
  };

  auto store_k = [&](int k, const float* yv) {
#pragma unroll
    for (int r = 0; r < 4; ++r) {
      if (!vr[r]) continue;
      if (USE_WS) {
#pragma unroll
        for (int t = 0; t < 4; ++t)  // coalesced: 16 lanes x 4B contiguous
          wsg[(size_t)qr[r] * (ND * NTOUT) + k * ND + 16 * t + c] = yv[r * 4 + t];
      } else {
#pragma unroll
        for (int t = 0; t < 4; ++t)
          outg[(size_t)qr[r] * (ND * NTOUT) + (16 * t + c) * NTOUT + k] = yv[r * 4 + t];
      }
    }
  };

  float tprev = tsg[b];
  store_k(0, y);

  float ksum[16], tmp[16];
  for (int k = 1; k < NTOUT; ++k) {
    float tnext = tsg[k * NB + b];
    float dt = tnext - tprev;
    int n = (int)ceilf(dt * 25.0f);  // h <= 0.04
    n = n < 1 ? 1 : n;
    float h = dt / (float)n;
    float h2 = 0.5f * h;
    float h6 = h * (1.0f / 6.0f);

    for (int s = 0; s < n; ++s) {
#pragma unroll
      for (int i = 0; i < 16; ++i) tmp[i] = y[i];
      feval(tmp);  // k1
#pragma unroll
      for (int i = 0; i < 16; ++i) { ksum[i] = tmp[i]; tmp[i] = fmaf(h2, tmp[i], y[i]); }
      feval(tmp);  // k2
#pragma unroll
      for (int i = 0; i < 16; ++i) { ksum[i] = fmaf(2.0f, tmp[i], ksum[i]); tmp[i] = fmaf(h2, tmp[i], y[i]); }
      feval(tmp);  // k3
#pragma unroll
      for (int i = 0; i < 16; ++i) { ksum[i] = fmaf(2.0f, tmp[i], ksum[i]); tmp[i] = fmaf(h, tmp[i], y[i]); }
      feval(tmp);  // k4
#pragma unroll
      for (int i = 0; i < 16; ++i) y[i] = fmaf(h6, ksum[i] + tmp[i], y[i]);
    }
    store_k(k, y);
    tprev = tnext;
  }
}

// ws[q][k][d] (coalesced writes in kernel1) -> out[q][d][k]
__global__ __launch_bounds__(256) void transpose_kernel(
    const float* __restrict__ ws, float* __restrict__ out) {
  __shared__ float lds[4 * 24 * 65];
  const int qb = blockIdx.x * 4;
  for (int i = threadIdx.x; i < 4 * 1536; i += 256) {
    int p = i / 1536, idx = i - p * 1536;  // idx = k*64 + d
    int k = idx >> 6, d = idx & 63;
    lds[p * 1560 + k * 65 + d] = ws[(size_t)(qb + p) * 1536 + idx];
  }
  __syncthreads();
  for (int i = threadIdx.x; i < 4 * 1536; i += 256) {
    int p = i / 1536, jdx = i - p * 1536;  // jdx = d*24 + k
    int d = jdx / 24, k = jdx - d * 24;
    out[(size_t)(qb + p) * 1536 + jdx] = lds[p * 1560 + k * 65 + d];
  }
}

extern "C" void kernel_launch(void* const* d_in, const int* in_sizes, int n_in,
                              void* d_out, int out_size, void* d_ws, size_t ws_size,
                              hipStream_t stream) {
  const float* y0 = (const float*)d_in[0];
  const float* ts = (const float*)d_in[1];
  const float* W1 = (const float*)d_in[2];
  const float* b1 = (const float*)d_in[3];
  const float* W2 = (const float*)d_in[4];
  const float* b2 = (const float*)d_in[5];
  float* out = (float*)d_out;
  float* ws = (float*)d_ws;

  const size_t need = (size_t)NB * NPT * ND * NTOUT * sizeof(float);  // 127.8 MB
  if (ws_size >= need) {
    hipLaunchKernelGGL((node_mfma_kernel<true>), dim3(K1_BLOCKS), dim3(256), 0,
                       stream, y0, ts, W1, b1, W2, b2, out, ws);
    hipLaunchKernelGGL(transpose_kernel, dim3(NB * NPT / 4), dim3(256), 0,
                       stream, ws, out);
  } else {
    hipLaunchKernelGGL((node_mfma_kernel<false>), dim3(K1_BLOCKS), dim3(256), 0,
                       stream, y0, ts, W1, b1, W2, b2, out, ws);
  }
}

// Round 5
// 448.958 us; speedup vs baseline: 6.6458x; 1.9264x over previous
//
#include <hip/hip_runtime.h>
#include <hip/hip_fp16.h>

// Neural-ODE via fixed-step RK4 (h <= 0.04), f(y) = tanh(y@W1+b1)@W2 + b2.
// One wave integrates 32 points with mfma_f32_32x32x16_f16, computing
//   H^T = tanh(W1^T @ Y^T + b1), F^T = W2^T @ H^T + b2   (cols = points)
// Weights/bias live in VGPRs as A-fragments (fp16). Layer-to-layer
// transposes are done IN REGISTER via cvt_pkrtz + permlane32_swap (no LDS,
// no barriers in the hot loop). LDS only stages coalesced output writes.
//
// Fragment maps (32x32x16, f16):
//   A: lane l holds A[row=l&31][k=(l>>5)*8 + j], j=0..7
//   B: lane l holds B[k=(l>>5)*8 + j][col=l&31]
//   C/D: lane l holds D[row=(reg&3)+8*(reg>>2)+4*(l>>5)][col=l&31]  (m74/m101)
// permlane32_swap(a,b): r0[l<32]=a[l], r0[l>=32]=b[l-32];
//                       r1[l<32]=a[l+32], r1[l>=32]=b[l]

#define NB 64
#define NPT 325
#define ND 64
#define NH 128
#define NTOUT 24
#define GP32 11                    // ceil(325/32) point-groups per batch
#define NTASK (NB * GP32)          // 704 waves, one block each

using f16x8 = __attribute__((ext_vector_type(8))) _Float16;
using f32x16 = __attribute__((ext_vector_type(16))) float;

__device__ __forceinline__ float fast_tanh(float x) {
  x = fminf(fmaxf(x, -12.0f), 12.0f);
  float e = __expf(2.0f * x);
  return (e - 1.0f) * __builtin_amdgcn_rcpf(e + 1.0f);
}

__device__ __forceinline__ unsigned pack2(float lo, float hi) {
  auto pk = __builtin_amdgcn_cvt_pkrtz(lo, hi);  // __fp16 ext_vector(2)
  return __builtin_bit_cast(unsigned, pk);
}

__device__ __forceinline__ void pswap(unsigned &a, unsigned &b) {
  auto r = __builtin_amdgcn_permlane32_swap(a, b, false, false);
  a = r[0];
  b = r[1];
}

union FragU { unsigned d[4]; f16x8 v; };

// 8 packed dwords (D-layout reg pairs) -> two B-fragments (16-row k-tiles)
__device__ __forceinline__ void two_frags(unsigned u[8], f16x8 &fa, f16x8 &fb) {
  pswap(u[0], u[2]); pswap(u[1], u[3]);
  pswap(u[4], u[6]); pswap(u[5], u[7]);
  FragU x0; x0.d[0] = u[0]; x0.d[1] = u[1]; x0.d[2] = u[2]; x0.d[3] = u[3];
  fa = x0.v;
  FragU x1; x1.d[0] = u[4]; x1.d[1] = u[5]; x1.d[2] = u[6]; x1.d[3] = u[7];
  fb = x1.v;
}

template <bool USE_WS>
__global__ __launch_bounds__(64, 1) void node_mfma32_kernel(
    const float* __restrict__ y0g, const float* __restrict__ tsg,
    const float* __restrict__ W1g, const float* __restrict__ b1g,
    const float* __restrict__ W2g, const float* __restrict__ b2g,
    float* __restrict__ outg, float* __restrict__ wsg) {
  __shared__ __align__(16) float sbuf[32 * 68];  // store staging, 8.7 KB
  const int lane = threadIdx.x & 63;
  const int c31 = lane & 31;
  const int hg = lane >> 5;

  const int task = blockIdx.x;
  const int b = task / GP32;
  const int p0 = (task - b * GP32) * 32;

  // ---- weights as fp16 A-fragments, VGPR-resident ----
  f16x8 wf1[4][4];  // W1^T [hid=128 x d=64]: rt row-tiles, kt k-tiles
#pragma unroll
  for (int rt = 0; rt < 4; ++rt)
#pragma unroll
    for (int kt = 0; kt < 4; ++kt) {
      f16x8 a;
#pragma unroll
      for (int j = 0; j < 8; ++j)
        a[j] = (_Float16)W1g[(16 * kt + 8 * hg + j) * NH + 32 * rt + c31];
      wf1[rt][kt] = a;
    }
  f16x8 wf2[2][8];  // W2^T [d=64 x hid=128]
#pragma unroll
  for (int rt = 0; rt < 2; ++rt)
#pragma unroll
    for (int kt = 0; kt < 8; ++kt) {
      f16x8 a;
#pragma unroll
      for (int j = 0; j < 8; ++j)
        a[j] = (_Float16)W2g[(16 * kt + 8 * hg + j) * ND + 32 * rt + c31];
      wf2[rt][kt] = a;
    }

  // ---- bias in fp32, matching C/D reg order (row off = (r&3)+8(r>>2)+4hg)
  float b1v[4][16], b2v[2][16];
#pragma unroll
  for (int rt = 0; rt < 4; ++rt)
#pragma unroll
    for (int r = 0; r < 16; ++r)
      b1v[rt][r] = b1g[32 * rt + (r & 3) + 8 * (r >> 2) + 4 * hg];
#pragma unroll
  for (int rt = 0; rt < 2; ++rt)
#pragma unroll
    for (int r = 0; r < 16; ++r)
      b2v[rt][r] = b2g[32 * rt + (r & 3) + 8 * (r >> 2) + 4 * hg];

  // ---- state Y^T[d][pt] in D-layout: y[16t + r] = Y[pt=c31][d = 32t+(r&3)+8(r>>2)+4hg]
  const int qc = b * NPT + min(p0 + c31, NPT - 1);
  float y[32], y5[32], f[32];
#pragma unroll
  for (int t = 0; t < 2; ++t)
#pragma unroll
    for (int rq = 0; rq < 4; ++rq) {
      float4 v = *(const float4*)&y0g[qc * ND + 32 * t + 8 * rq + 4 * hg];
      y[16 * t + 4 * rq + 0] = v.x;
      y[16 * t + 4 * rq + 1] = v.y;
      y[16 * t + 4 * rq + 2] = v.z;
      y[16 * t + 4 * rq + 3] = v.w;
    }

  // build B-fragments of current state (cols = points)
  auto make_frags = [&](auto&& val, f16x8 yb[4]) {
#pragma unroll
    for (int t = 0; t < 2; ++t) {
      unsigned u[8];
#pragma unroll
      for (int p = 0; p < 8; ++p)
        u[p] = pack2(val(16 * t + 2 * p), val(16 * t + 2 * p + 1));
      two_frags(u, yb[2 * t], yb[2 * t + 1]);
    }
  };

  auto feval = [&](const f16x8 yb[4]) {
    // layer 1: H^T tiles, 4 independent accumulate chains
    f32x16 acc1[4];
#pragma unroll
    for (int rt = 0; rt < 4; ++rt)
#pragma unroll
      for (int r = 0; r < 16; ++r) acc1[rt][r] = b1v[rt][r];
#pragma unroll
    for (int kt = 0; kt < 4; ++kt)
#pragma unroll
      for (int rt = 0; rt < 4; ++rt)
        acc1[rt] = __builtin_amdgcn_mfma_f32_32x32x16_f16(wf1[rt][kt], yb[kt], acc1[rt], 0, 0, 0);

    // tanh -> fp16 -> in-register transpose to B-fragments
    f16x8 hb[8];
#pragma unroll
    for (int rt = 0; rt < 4; ++rt) {
      unsigned u[8];
#pragma unroll
      for (int p = 0; p < 8; ++p)
        u[p] = pack2(fast_tanh(acc1[rt][2 * p]), fast_tanh(acc1[rt][2 * p + 1]));
      two_frags(u, hb[2 * rt], hb[2 * rt + 1]);
    }

    // layer 2: split-K (4 independent chains of 4)
    f32x16 accA[2], accB[2];
#pragma unroll
    for (int rt = 0; rt < 2; ++rt)
#pragma unroll
      for (int r = 0; r < 16; ++r) {
        accA[rt][r] = b2v[rt][r];
        accB[rt][r] = 0.0f;
      }
#pragma unroll
    for (int kt = 0; kt < 4; ++kt)
#pragma unroll
      for (int rt = 0; rt < 2; ++rt) {
        accA[rt] = __builtin_amdgcn_mfma_f32_32x32x16_f16(wf2[rt][kt], hb[kt], accA[rt], 0, 0, 0);
        accB[rt] = __builtin_amdgcn_mfma_f32_32x32x16_f16(wf2[rt][kt + 4], hb[kt + 4], accB[rt], 0, 0, 0);
      }
#pragma unroll
    for (int t = 0; t < 2; ++t)
#pragma unroll
      for (int r = 0; r < 16; ++r) f[16 * t + r] = accA[t][r] + accB[t][r];
  };

  auto store_k = [&](int k) {
    // stage D-layout -> [pt][d] in LDS (single wave: in-order, no barrier)
#pragma unroll
    for (int t = 0; t < 2; ++t)
#pragma unroll
      for (int rq = 0; rq < 4; ++rq) {
        float4 v = make_float4(y[16 * t + 4 * rq], y[16 * t + 4 * rq + 1],
                               y[16 * t + 4 * rq + 2], y[16 * t + 4 * rq + 3]);
        *(float4*)&sbuf[c31 * 68 + 32 * t + 8 * rq + 4 * hg] = v;
      }
    const int pt = lane >> 1, half = lane & 1;
    const int q = b * NPT + min(p0 + pt, NPT - 1);  // clamped lanes dup-write same value
#pragma unroll
    for (int i = 0; i < 8; ++i) {
      float4 v = *(const float4*)&sbuf[pt * 68 + half * 32 + 4 * i];
      if (USE_WS) {
        *(float4*)&wsg[(size_t)q * (ND * NTOUT) + k * ND + half * 32 + 4 * i] = v;
      } else {
        const size_t base = (size_t)q * (ND * NTOUT);
        const int d0 = half * 32 + 4 * i;
        outg[base + (d0 + 0) * NTOUT + k] = v.x;
        outg[base + (d0 + 1) * NTOUT + k] = v.y;
        outg[base + (d0 + 2) * NTOUT + k] = v.z;
        outg[base + (d0 + 3) * NTOUT + k] = v.w;
      }
    }
  };

  float tprev = tsg[b];
  store_k(0);

  f16x8 yb[4];
  for (int k = 1; k < NTOUT; ++k) {
    float tnext = tsg[k * NB + b];
    float dt = tnext - tprev;
    int n = (int)ceilf(dt * 25.0f);  // h <= 0.04
    n = n < 1 ? 1 : n;
    float h = dt / (float)n;
    float h2 = 0.5f * h;
    float h6 = h * (1.0f / 6.0f);
    float h3 = 2.0f * h6;

    for (int s = 0; s < n; ++s) {
      make_frags([&](int i) { return y[i]; }, yb);
      feval(yb);  // k1
#pragma unroll
      for (int i = 0; i < 32; ++i) y5[i] = fmaf(h6, f[i], y[i]);
      make_frags([&](int i) { return fmaf(h2, f[i], y[i]); }, yb);
      feval(yb);  // k2
#pragma unroll
      for (int i = 0; i < 32; ++i) y5[i] = fmaf(h3, f[i], y5[i]);
      make_frags([&](int i) { return fmaf(h2, f[i], y[i]); }, yb);
      feval(yb);  // k3
#pragma unroll
      for (int i = 0; i < 32; ++i) y5[i] = fmaf(h3, f[i], y5[i]);
      make_frags([&](int i) { return fmaf(h, f[i], y[i]); }, yb);
      feval(yb);  // k4
#pragma unroll
      for (int i = 0; i < 32; ++i) y[i] = fmaf(h6, f[i], y5[i]);
    }
    store_k(k);
    tprev = tnext;
  }
}

// ws[q][k][d] -> out[q][d][k]
__global__ __launch_bounds__(256) void transpose_kernel(
    const float* __restrict__ ws, float* __restrict__ out) {
  __shared__ float lds[4 * 24 * 65];
  const int qb = blockIdx.x * 4;
  for (int i = threadIdx.x; i < 4 * 1536; i += 256) {
    int p = i / 1536, idx = i - p * 1536;  // idx = k*64 + d
    int k = idx >> 6, d = idx & 63;
    lds[p * 1560 + k * 65 + d] = ws[(size_t)(qb + p) * 1536 + idx];
  }
  __syncthreads();
  for (int i = threadIdx.x; i < 4 * 1536; i += 256) {
    int p = i / 1536, jdx = i - p * 1536;  // jdx = d*24 + k
    int d = jdx / 24, k = jdx - d * 24;
    out[(size_t)(qb + p) * 1536 + jdx] = lds[p * 1560 + k * 65 + d];
  }
}

extern "C" void kernel_launch(void* const* d_in, const int* in_sizes, int n_in,
                              void* d_out, int out_size, void* d_ws, size_t ws_size,
                              hipStream_t stream) {
  const float* y0 = (const float*)d_in[0];
  const float* ts = (const float*)d_in[1];
  const float* W1 = (const float*)d_in[2];
  const float* b1 = (const float*)d_in[3];
  const float* W2 = (const float*)d_in[4];
  const float* b2 = (const float*)d_in[5];
  float* out = (float*)d_out;
  float* ws = (float*)d_ws;

  const size_t need = (size_t)NB * NPT * ND * NTOUT * sizeof(float);  // 127.8 MB
  if (ws_size >= need) {
    hipLaunchKernelGGL((node_mfma32_kernel<true>), dim3(NTASK), dim3(64), 0,
                       stream, y0, ts, W1, b1, W2, b2, out, ws);
    hipLaunchKernelGGL(transpose_kernel, dim3(NB * NPT / 4), dim3(256), 0,
                       stream, ws, out);
  } else {
    hipLaunchKernelGGL((node_mfma32_kernel<false>), dim3(NTASK), dim3(64), 0,
                       stream, y0, ts, W1, b1, W2, b2, out, ws);
  }
}